// Round 4
// baseline (242.464 us; speedup 1.0000x reference)
//
#include <hip/hip_runtime.h>
#include <hip/hip_bf16.h>

// Problem dims (fixed by reference)
#define B_ROWS   8192
#define K_DIM    2048
#define OUT_COLS 4096
#define EPS      1e-5f

// GEMM tile: 256x256, BK=64, 8 waves (2M x 4N), mfma 32x32x16, frag-order LDS
#define BM 256
#define BN 256
#define BK 64
#define NT (K_DIM / BK)   // 32 K-tiles

using f32x16 = __attribute__((ext_vector_type(16))) float;
using bf16x8 = __attribute__((ext_vector_type(8))) short;   // 8 bf16 = 4 VGPRs

__device__ __forceinline__ unsigned short f2bf_rn(float f) {
    unsigned u = __builtin_bit_cast(unsigned, f);
    u += 0x7FFFu + ((u >> 16) & 1u);   // RNE (inputs finite)
    return (unsigned short)(u >> 16);
}

// single conversion kernel for both x and w
__global__ void cvt_all(const float* __restrict__ x, const float* __restrict__ w,
                        unsigned short* __restrict__ xb, unsigned short* __restrict__ wb) {
    const int n4x = (B_ROWS * K_DIM) / 4;
    const int n4w = (OUT_COLS * K_DIM) / 4;
    int stride = gridDim.x * blockDim.x;
    for (int i = blockIdx.x * blockDim.x + threadIdx.x; i < n4x + n4w; i += stride) {
        const float4* src; ushort4* dst; int j;
        if (i < n4x) { src = (const float4*)x; dst = (ushort4*)xb; j = i; }
        else         { src = (const float4*)w; dst = (ushort4*)wb; j = i - n4x; }
        float4 v = src[j];
        ushort4 r;
        r.x = f2bf_rn(v.x); r.y = f2bf_rn(v.y); r.z = f2bf_rn(v.z); r.w = f2bf_rn(v.w);
        dst[j] = r;
    }
}

__device__ __forceinline__ void gload16(const unsigned short* src, unsigned short* lds) {
    __builtin_amdgcn_global_load_lds((const __attribute__((address_space(1))) void*)src,
                                     (__attribute__((address_space(3))) void*)lds,
                                     16, 0, 0);
}

// stage one half-tile (128 rows x 64 k): LDS dest linear in fragment-read order,
// global source permuted to match (slot s -> row mt*32+(s&31), k ks*16+((s>>5)&1)*8)
#define STA(BUF, H, KT) do {                                                        \
    gload16(Ag + (H)*262144 + (KT)*64 + goff0, &As[BUF][(H)*8192 + lds0]);          \
    gload16(Ag + (H)*262144 + (KT)*64 + goff1, &As[BUF][(H)*8192 + lds1]);          \
  } while (0)
#define STB(BUF, H, KT) do {                                                        \
    gload16(Bg + (H)*262144 + (KT)*64 + goff0, &Bs[BUF][(H)*8192 + lds0]);          \
    gload16(Bg + (H)*262144 + (KT)*64 + goff1, &Bs[BUF][(H)*8192 + lds1]);          \
  } while (0)

// A-quadrant read: 4 ds_read_b128, all base+imm (consumed NEXT phase, ping-pong)
#define RD_A(SLOT, BUFP, KS) do {                                                   \
    _Pragma("unroll") for (int mt = 0; mt < 4; ++mt)                                \
      af[SLOT][mt] = *(const bf16x8*)&(BUFP)[abase + mt*2048 + (KS)*512];           \
  } while (0)

// bulk B-fragment read for one tile: 8 ds_read_b128 (consumed starting next phase)
#define RD_Bb(BUFP) do {                                                            \
    _Pragma("unroll") for (int nt = 0; nt < 2; ++nt)                                \
      _Pragma("unroll") for (int ks = 0; ks < 4; ++ks)                              \
        bb[nt][ks] = *(const bf16x8*)&(BUFP)[bbase + nt*2048 + ks*512];             \
  } while (0)

#define MFMA8(SLOT, KS) do {                                                        \
    __builtin_amdgcn_s_setprio(1);                                                  \
    _Pragma("unroll") for (int mt = 0; mt < 4; ++mt)                                \
      _Pragma("unroll") for (int nt = 0; nt < 2; ++nt)                              \
        acc[mt][nt] = __builtin_amdgcn_mfma_f32_32x32x16_bf16(                      \
            af[SLOT][mt], bb[nt][KS], acc[mt][nt], 0, 0, 0);                        \
    __builtin_amdgcn_s_setprio(0);                                                  \
  } while (0)

#define VW4  asm volatile("s_waitcnt vmcnt(4)" ::: "memory")
#define BAR  __builtin_amdgcn_s_barrier()

__global__ __launch_bounds__(512, 2) void gemm_gn(const unsigned short* __restrict__ A,
                                                  const unsigned short* __restrict__ Bw,
                                                  const float* __restrict__ bias,
                                                  float* __restrict__ out) {
    __shared__ __align__(16) unsigned short As[2][16384];   // 2 bufs x (2 halves x 8192)
    __shared__ __align__(16) unsigned short Bs[2][16384];

    const int tid  = threadIdx.x;
    const int lane = tid & 63;
    const int wave = tid >> 6;        // 0..7
    const int wr   = wave >> 2;       // 0..1 (M)
    const int wcn  = wave & 3;        // 0..3 (N)
    const int l32  = lane & 31;
    const int lhi  = lane >> 5;

    // T1: XCD-aware bijective swizzle (512 % 8 == 0)
    const int bid  = blockIdx.x;
    const int swz  = (bid & 7) * (gridDim.x >> 3) + (bid >> 3);
    const int brow = swz >> 4;        // 0..31
    const int bcol = swz & 15;        // 0..15

    // staging: thread covers slots s0 = tid, s1 = tid+512 of each 1024-slot half-tile
    int goff0, goff1, lds0, lds1;
    {
        int s0 = tid, s1 = tid + 512;
        goff0 = ((s0 >> 8) * 32 + (s0 & 31)) * K_DIM + ((s0 >> 6) & 3) * 16 + ((s0 >> 5) & 1) * 8;
        goff1 = ((s1 >> 8) * 32 + (s1 & 31)) * K_DIM + ((s1 >> 6) & 3) * 16 + ((s1 >> 5) & 1) * 8;
        lds0  = s0 * 8;
        lds1  = s1 * 8;
    }
    const unsigned short* Ag = A  + (size_t)brow * BM * K_DIM;
    const unsigned short* Bg = Bw + (size_t)bcol * BN * K_DIM;

    // fragment-read bases (ushort units): one VGPR each, all reads base+imm16
    const int abase = wr * 8192 + lane * 8;
    const int bbase = (wcn >> 1) * 8192 + (wcn & 1) * 2 * 2048 + lane * 8;

    const unsigned short* A0p = &As[0][0];
    const unsigned short* A1p = &As[1][0];
    const unsigned short* B0p = &Bs[0][0];
    const unsigned short* B1p = &Bs[1][0];

    f32x16 acc[4][2] = {};
    bf16x8 af[2][4];
    bf16x8 bb[2][4];

    // ---- prologue: A(0), B(0), B(1); keep B(1)'s 4 loads in flight
    STA(0, 0, 0); STA(0, 1, 0);
    STB(0, 0, 0); STB(0, 1, 0);
    STB(1, 0, 1); STB(1, 1, 1);
    VW4;                       // A(0), B(0) resident
    BAR;
    RD_A(0, A0p, 0);
    RD_Bb(B0p);

    #pragma unroll 1
    for (int tt = 0; tt < NT; tt += 2) {
        const int k1 = (tt + 1) & (NT - 1);
        const int k2 = (tt + 2) & (NT - 1);
        const int k3 = (tt + 3) & (NT - 1);
        // ---- tile tt (buf0) ----
        RD_A(1, A0p, 1); STA(1, 0, k1);                MFMA8(0, 0);             BAR;
        RD_A(0, A0p, 2); STA(1, 1, k1); STB(0, 0, k2); MFMA8(1, 1);             BAR;
        RD_A(1, A0p, 3); STB(0, 1, k2);                MFMA8(0, 2); VW4;        BAR;
        RD_A(0, A1p, 0);                               MFMA8(1, 3); RD_Bb(B1p); BAR;
        // ---- tile tt+1 (buf1) ----
        RD_A(1, A1p, 1); STA(0, 0, k2);                MFMA8(0, 0);             BAR;
        RD_A(0, A1p, 2); STA(0, 1, k2); STB(1, 0, k3); MFMA8(1, 1);             BAR;
        RD_A(1, A1p, 3); STB(1, 1, k3);                MFMA8(0, 2); VW4;        BAR;
        RD_A(0, A0p, 0);                               MFMA8(1, 3); RD_Bb(B0p); BAR;
    }

    // ---- epilogue: drain dummy stages, reuse LDS for GroupNorm reduction ----
    asm volatile("s_waitcnt vmcnt(0)" ::: "memory");
    __syncthreads();
    float* red = (float*)&As[0][0];   // [256 rows][4 wcn][2] = 8 KB

    float bv[2];
    #pragma unroll
    for (int nt = 0; nt < 2; ++nt)
        bv[nt] = bias[bcol * BN + wcn * 64 + nt * 32 + l32];

    // C/D layout (32x32): col = lane&31, row = (reg&3) + 8*(reg>>2) + 4*(lane>>5)
    // pass 1: bias + per-row partial sums over this wave's 64 cols, 32-lane reduce
    #pragma unroll
    for (int mt = 0; mt < 4; ++mt) {
        #pragma unroll
        for (int reg = 0; reg < 16; ++reg) {
            float v0 = acc[mt][0][reg] + bv[0];
            float v1 = acc[mt][1][reg] + bv[1];
            acc[mt][0][reg] = v0;
            acc[mt][1][reg] = v1;
            float s = v0 + v1, s2 = v0 * v0 + v1 * v1;
            #pragma unroll
            for (int o = 1; o < 32; o <<= 1) {
                s  += __shfl_xor(s,  o);
                s2 += __shfl_xor(s2, o);
            }
            if (l32 == 0) {
                int r = wr * 128 + mt * 32 + (reg & 3) + 8 * (reg >> 2) + 4 * lhi;
                red[r * 8 + wcn * 2 + 0] = s;
                red[r * 8 + wcn * 2 + 1] = s2;
            }
        }
    }
    __syncthreads();

    // pass 2: combine the wave pair covering each 128-col group, normalize, clip, store
    const int p2 = (wcn & 2) * 2;
    #pragma unroll
    for (int mt = 0; mt < 4; ++mt) {
        #pragma unroll
        for (int reg = 0; reg < 16; ++reg) {
            const int r = wr * 128 + mt * 32 + (reg & 3) + 8 * (reg >> 2) + 4 * lhi;
            const float s  = red[r * 8 + p2 + 0] + red[r * 8 + p2 + 2];
            const float s2 = red[r * 8 + p2 + 1] + red[r * 8 + p2 + 3];
            const float mean = s * (1.0f / 128.0f);
            const float var  = s2 * (1.0f / 128.0f) - mean * mean;
            const float rstd = rsqrtf(var + EPS);
            float* orow = out + (size_t)(brow * BM + r) * OUT_COLS + bcol * BN + wcn * 64 + l32;
            #pragma unroll
            for (int nt = 0; nt < 2; ++nt) {
                float v = (acc[mt][nt][reg] - mean) * rstd;
                v = fminf(fmaxf(v, -1.0f), 1.0f);
                orow[nt * 32] = v;
            }
        }
    }
}

extern "C" void kernel_launch(void* const* d_in, const int* in_sizes, int n_in,
                              void* d_out, int out_size, void* d_ws, size_t ws_size,
                              hipStream_t stream) {
    const float* x    = (const float*)d_in[0];   // [8192][2048]
    const float* w    = (const float*)d_in[1];   // [4096][2048]
    const float* bias = (const float*)d_in[2];   // [4096]
    float* out        = (float*)d_out;           // [8192][4096]

    unsigned short* xb = (unsigned short*)d_ws;
    unsigned short* wb = xb + (size_t)B_ROWS * K_DIM;

    cvt_all<<<3072, 256, 0, stream>>>(x, w, xb, wb);

    dim3 grid((B_ROWS / BM) * (OUT_COLS / BN));   // 32 * 16 = 512
    gemm_gn<<<grid, 512, 0, stream>>>(xb, wb, bias, out);
}

// Round 5
// 175.740 us; speedup vs baseline: 1.3797x; 1.3797x over previous
//
#include <hip/hip_runtime.h>
#include <hip/hip_bf16.h>

// Problem dims (fixed by reference)
#define B_ROWS   8192
#define K_DIM    2048
#define OUT_COLS 4096
#define EPS      1e-5f

// GEMM tile: 256x256, BK=64, 8 waves (2M x 4N), mfma 32x32x16
// Staging: round-3 scheme (linear LDS, per-row XOR-swizzled coalesced source)
#define BM 256
#define BN 256
#define BK 64
#define NT (K_DIM / BK)   // 32 K-tiles

using f32x16 = __attribute__((ext_vector_type(16))) float;
using bf16x8 = __attribute__((ext_vector_type(8))) short;   // 8 bf16 = 4 VGPRs

__device__ __forceinline__ unsigned short f2bf_rn(float f) {
    unsigned u = __builtin_bit_cast(unsigned, f);
    u += 0x7FFFu + ((u >> 16) & 1u);   // RNE (inputs finite)
    return (unsigned short)(u >> 16);
}

__global__ void cvt_all(const float* __restrict__ x, const float* __restrict__ w,
                        unsigned short* __restrict__ xb, unsigned short* __restrict__ wb) {
    const int n4x = (B_ROWS * K_DIM) / 4;
    const int n4w = (OUT_COLS * K_DIM) / 4;
    int stride = gridDim.x * blockDim.x;
    for (int i = blockIdx.x * blockDim.x + threadIdx.x; i < n4x + n4w; i += stride) {
        const float4* src; ushort4* dst; int j;
        if (i < n4x) { src = (const float4*)x; dst = (ushort4*)xb; j = i; }
        else         { src = (const float4*)w; dst = (ushort4*)wb; j = i - n4x; }
        float4 v = src[j];
        ushort4 r;
        r.x = f2bf_rn(v.x); r.y = f2bf_rn(v.y); r.z = f2bf_rn(v.z); r.w = f2bf_rn(v.w);
        dst[j] = r;
    }
}

__device__ __forceinline__ void gload16(const unsigned short* src, unsigned short* lds) {
    __builtin_amdgcn_global_load_lds((const __attribute__((address_space(1))) void*)src,
                                     (__attribute__((address_space(3))) void*)lds,
                                     16, 0, 0);
}

// DPP row_ror reduction over 16 lanes + ds_swizzle xor16 => 32-lane sum in all lanes
__device__ __forceinline__ float rowsum32(float v) {
    int x;
    x = __builtin_amdgcn_update_dpp(0, __builtin_bit_cast(int, v), 0x121, 0xF, 0xF, true);
    v += __builtin_bit_cast(float, x);   // ror:1
    x = __builtin_amdgcn_update_dpp(0, __builtin_bit_cast(int, v), 0x122, 0xF, 0xF, true);
    v += __builtin_bit_cast(float, x);   // ror:2
    x = __builtin_amdgcn_update_dpp(0, __builtin_bit_cast(int, v), 0x124, 0xF, 0xF, true);
    v += __builtin_bit_cast(float, x);   // ror:4
    x = __builtin_amdgcn_update_dpp(0, __builtin_bit_cast(int, v), 0x128, 0xF, 0xF, true);
    v += __builtin_bit_cast(float, x);   // ror:8
    x = __builtin_amdgcn_ds_swizzle(__builtin_bit_cast(int, v), 0x401F); // xor 16
    v += __builtin_bit_cast(float, x);
    return v;
}

// stage one half-tile (128 rows x 64 k): linear LDS dest, per-row XOR-permuted global src
#define STA(BUF, H, KT) do {                                                        \
    gload16(Ag + (H)*262144 + (KT)*64 + goff0, &As[BUF][(H)*8192 + lds0]);          \
    gload16(Ag + (H)*262144 + (KT)*64 + goff1, &As[BUF][(H)*8192 + lds1]);          \
  } while (0)
#define STB(BUF, H, KT) do {                                                        \
    gload16(Bg + (H)*262144 + (KT)*64 + goff0, &Bs[BUF][(H)*8192 + lds0]);          \
    gload16(Bg + (H)*262144 + (KT)*64 + goff1, &Bs[BUF][(H)*8192 + lds1]);          \
  } while (0)

// A read for k-slice KS: 4 ds_read_b128 (one per 32-row block), swizzled chunk offset
#define RD_A(SLOT, BUFP, KS) do {                                                   \
    _Pragma("unroll") for (int mt = 0; mt < 4; ++mt)                                \
      af[SLOT][mt] = *(const bf16x8*)&(BUFP)[abase + mt*2048 + cs[KS]];             \
  } while (0)

// bulk B read for one tile: 8 ds_read_b128
#define RD_Bb(BUFP) do {                                                            \
    _Pragma("unroll") for (int nt = 0; nt < 2; ++nt)                                \
      _Pragma("unroll") for (int ks = 0; ks < 4; ++ks)                              \
        bb[nt][ks] = *(const bf16x8*)&(BUFP)[bbase + nt*2048 + cs[ks]];             \
  } while (0)

#define MFMA8(SLOT, KS) do {                                                        \
    __builtin_amdgcn_s_setprio(1);                                                  \
    _Pragma("unroll") for (int mt = 0; mt < 4; ++mt)                                \
      _Pragma("unroll") for (int nt = 0; nt < 2; ++nt)                              \
        acc[mt][nt] = __builtin_amdgcn_mfma_f32_32x32x16_bf16(                      \
            af[SLOT][mt], bb[nt][KS], acc[mt][nt], 0, 0, 0);                        \
    __builtin_amdgcn_s_setprio(0);                                                  \
  } while (0)

#define VW4  asm volatile("s_waitcnt vmcnt(4)" ::: "memory")
#define BAR  __builtin_amdgcn_s_barrier()

__global__ __launch_bounds__(512, 2) void gemm_gn(const unsigned short* __restrict__ A,
                                                  const unsigned short* __restrict__ Bw,
                                                  const float* __restrict__ bias,
                                                  float* __restrict__ out) {
    __shared__ __align__(16) unsigned short As[2][16384];   // 2 x 32 KB
    __shared__ __align__(16) unsigned short Bs[2][16384];

    const int tid  = threadIdx.x;
    const int lane = tid & 63;
    const int wave = tid >> 6;        // 0..7
    const int wr   = wave >> 2;       // 0..1 (M)
    const int wcn  = wave & 3;        // 0..3 (N)
    const int l32  = lane & 31;
    const int lhi  = lane >> 5;

    // T1: XCD-aware bijective swizzle (512 % 8 == 0)
    const int bid  = blockIdx.x;
    const int swz  = (bid & 7) * (gridDim.x >> 3) + (bid >> 3);
    const int brow = swz >> 4;        // 0..31
    const int bcol = swz & 15;        // 0..15

    // staging offsets (round-3 scheme): slot f -> row f>>3, chunk (f&7)^(row&7)
    int goff0, goff1, lds0, lds1;
    {
        int f0 = tid;          int r0 = f0 >> 3;
        int f1 = 512 + tid;    int r1 = f1 >> 3;
        goff0 = r0 * K_DIM + (((f0 & 7) ^ (r0 & 7)) * 8);
        goff1 = r1 * K_DIM + (((f1 & 7) ^ (r1 & 7)) * 8);
        lds0  = f0 * 8;
        lds1  = f1 * 8;
    }
    const unsigned short* Ag = A  + (size_t)brow * BM * K_DIM;
    const unsigned short* Bg = Bw + (size_t)bcol * BN * K_DIM;

    // fragment-read offsets: row rr (within 128-row half), chunk c = ks*2+lhi,
    // ushort off = rr*64 + ((c ^ (rr&7))*8);  rr&7 == l32&7 for all frags
    int cs[4];
    #pragma unroll
    for (int ks = 0; ks < 4; ++ks)
        cs[ks] = (((ks * 2 + lhi) ^ (l32 & 7)) * 8);
    const int abase = wr * 8192 + l32 * 64;
    const int bbase = (wcn >> 1) * 8192 + ((wcn & 1) * 64 + l32) * 64;

    const unsigned short* A0p = &As[0][0];
    const unsigned short* A1p = &As[1][0];
    const unsigned short* B0p = &Bs[0][0];
    const unsigned short* B1p = &Bs[1][0];

    // bias folded into accumulator init: every C-reg of acc[mt][nt] is a row of col
    // (wcn*64 + nt*32 + l32), so init all 16 regs with that column's bias.
    float bv[2];
    #pragma unroll
    for (int nt = 0; nt < 2; ++nt)
        bv[nt] = bias[bcol * BN + wcn * 64 + nt * 32 + l32];

    f32x16 acc[4][2];
    #pragma unroll
    for (int mt = 0; mt < 4; ++mt)
        #pragma unroll
        for (int nt = 0; nt < 2; ++nt)
            #pragma unroll
            for (int reg = 0; reg < 16; ++reg)
                acc[mt][nt][reg] = bv[nt];

    bf16x8 af[2][4];
    bf16x8 bb[2][4];

    // ---- prologue: A(0), B(0), B(1); keep B(1)'s 4 loads in flight
    STA(0, 0, 0); STA(0, 1, 0);
    STB(0, 0, 0); STB(0, 1, 0);
    STB(1, 0, 1); STB(1, 1, 1);
    VW4;                       // A(0), B(0) resident
    BAR;
    RD_A(0, A0p, 0);
    RD_Bb(B0p);

    #pragma unroll 1
    for (int tt = 0; tt < NT; tt += 2) {
        const int k1 = (tt + 1) & (NT - 1);
        const int k2 = (tt + 2) & (NT - 1);
        const int k3 = (tt + 3) & (NT - 1);
        // ---- tile tt (buf0) ----
        RD_A(1, A0p, 1); STA(1, 0, k1);                MFMA8(0, 0);             BAR;
        RD_A(0, A0p, 2); STA(1, 1, k1); STB(0, 0, k2); MFMA8(1, 1);             BAR;
        RD_A(1, A0p, 3); STB(0, 1, k2);                MFMA8(0, 2); VW4;        BAR;
        RD_A(0, A1p, 0);                               MFMA8(1, 3); RD_Bb(B1p); BAR;
        // ---- tile tt+1 (buf1) ----
        RD_A(1, A1p, 1); STA(0, 0, k2);                MFMA8(0, 0);             BAR;
        RD_A(0, A1p, 2); STA(0, 1, k2); STB(1, 0, k3); MFMA8(1, 1);             BAR;
        RD_A(1, A1p, 3); STB(1, 1, k3);                MFMA8(0, 2); VW4;        BAR;
        RD_A(0, A0p, 0);                               MFMA8(1, 3); RD_Bb(B0p); BAR;
    }

    // ---- epilogue: GroupNorm over 128-col groups (block-local), clip, store ----
    asm volatile("s_waitcnt vmcnt(0)" ::: "memory");
    __syncthreads();
    float* red = (float*)&As[0][0];   // [256 rows][4 wcn][2] f32 = 8 KB

    // pass 1: per-row (s, s2) over this wave's 64 cols via DPP+swizzle butterfly
    // C/D layout (32x32): col = lane&31, row = (reg&3) + 8*(reg>>2) + 4*(lane>>5)
    #pragma unroll
    for (int mt = 0; mt < 4; ++mt) {
        #pragma unroll
        for (int reg = 0; reg < 16; ++reg) {
            float v0 = acc[mt][0][reg];
            float v1 = acc[mt][1][reg];
            float s  = rowsum32(v0 + v1);
            float s2 = rowsum32(v0 * v0 + v1 * v1);
            if (l32 == 0) {
                int r = wr * 128 + mt * 32 + (reg & 3) + 8 * (reg >> 2) + 4 * lhi;
                red[r * 8 + wcn * 2 + 0] = s;
                red[r * 8 + wcn * 2 + 1] = s2;
            }
        }
    }
    __syncthreads();

    // pass 2: combine wave pair per 128-col group (uniform-address b128 = broadcast)
    const int p2 = (wcn & 2) * 2;
    #pragma unroll
    for (int mt = 0; mt < 4; ++mt) {
        #pragma unroll
        for (int reg = 0; reg < 16; ++reg) {
            const int r = wr * 128 + mt * 32 + (reg & 3) + 8 * (reg >> 2) + 4 * lhi;
            const float4 q = *(const float4*)&red[r * 8 + p2];
            const float s    = q.x + q.z;
            const float s2   = q.y + q.w;
            const float mean = s * (1.0f / 128.0f);
            const float var  = s2 * (1.0f / 128.0f) - mean * mean;
            const float rstd = rsqrtf(var + EPS);
            float* orow = out + (size_t)(brow * BM + r) * OUT_COLS + bcol * BN + wcn * 64 + l32;
            #pragma unroll
            for (int nt = 0; nt < 2; ++nt) {
                float v = (acc[mt][nt][reg] - mean) * rstd;
                v = fminf(fmaxf(v, -1.0f), 1.0f);
                orow[nt * 32] = v;
            }
        }
    }
}

extern "C" void kernel_launch(void* const* d_in, const int* in_sizes, int n_in,
                              void* d_out, int out_size, void* d_ws, size_t ws_size,
                              hipStream_t stream) {
    const float* x    = (const float*)d_in[0];   // [8192][2048]
    const float* w    = (const float*)d_in[1];   // [4096][2048]
    const float* bias = (const float*)d_in[2];   // [4096]
    float* out        = (float*)d_out;           // [8192][4096]

    unsigned short* xb = (unsigned short*)d_ws;
    unsigned short* wb = xb + (size_t)B_ROWS * K_DIM;

    cvt_all<<<3072, 256, 0, stream>>>(x, w, xb, wb);

    dim3 grid((B_ROWS / BM) * (OUT_COLS / BN));   // 32 * 16 = 512
    gemm_gn<<<grid, 512, 0, stream>>>(xb, wb, bias, out);
}